// Round 1
// baseline (335.577 us; speedup 1.0000x reference)
//
#include <hip/hip_runtime.h>

// Problem constants (fixed by setup_inputs)
#define NSAMP 16384   // N
#define BB    4       // batch
#define C2D   128
#define C3D   128
#define HH    96
#define WW    160
#define COUT  128
#define KK    256     // fan_in = C2D + C3D
#define TN    64      // samples per block
#define HW    (HH*WW)

// One block: batch b, samples [n0, n0+TN). 256 threads = 4 waves.
// LDS: cat[KK][TN] fp32 (64 KB) -> 2 blocks/CU.
__global__ __launch_bounds__(256, 2) void fuse_kernel(
    const float* __restrict__ xy,     // [B,2,N]
    const float* __restrict__ f2d,    // [B,C2D,H,W]
    const float* __restrict__ f3d,    // [B,C3D,N]
    const float* __restrict__ Wm,     // [COUT,KK]
    const float* __restrict__ bias,   // [COUT]
    float* __restrict__ out)          // [B,COUT,N]
{
    __shared__ float cat[KK][TN];     // cat[k][j], j = sample in tile
    __shared__ float sw[4][TN];       // corner weights (validity folded in)
    __shared__ int   soff[4][TN];     // corner offsets into one channel plane

    const int tid  = threadIdx.x;
    const int lane = tid & 63;
    const int wv   = tid >> 6;        // wave id 0..3
    const int blk  = blockIdx.x;
    const int b    = blk >> 8;        // N/TN = 256 tiles per batch
    const int n0   = (blk & 255) * TN;

    // ---- Phase 0: bilinear params for the 64 samples ----
    if (tid < TN) {
        const int n = n0 + tid;
        float x = xy[((size_t)b * 2 + 0) * NSAMP + n];
        float y = xy[((size_t)b * 2 + 1) * NSAMP + n];
        float xf = floorf(x), yf = floorf(y);
        float wx1 = x - xf, wy1 = y - yf;
        float wx0 = 1.0f - wx1, wy0 = 1.0f - wy1;
        int x0 = (int)xf, y0 = (int)yf;
        int x1 = x0 + 1, y1 = y0 + 1;
        // zero weights for out-of-bounds corners (reference: valid-mask * value)
        if (x0 < 0 || x0 > WW - 1) wx0 = 0.0f;
        if (x1 < 0 || x1 > WW - 1) wx1 = 0.0f;
        if (y0 < 0 || y0 > HH - 1) wy0 = 0.0f;
        if (y1 < 0 || y1 > HH - 1) wy1 = 0.0f;
        x0 = min(max(x0, 0), WW - 1);
        x1 = min(max(x1, 0), WW - 1);
        y0 = min(max(y0, 0), HH - 1);
        y1 = min(max(y1, 0), HH - 1);
        sw[0][tid] = wx0 * wy0;
        sw[1][tid] = wx1 * wy0;
        sw[2][tid] = wx0 * wy1;
        sw[3][tid] = wx1 * wy1;
        soff[0][tid] = y0 * WW + x0;
        soff[1][tid] = y0 * WW + x1;
        soff[2][tid] = y1 * WW + x0;
        soff[3][tid] = y1 * WW + x1;
    }
    __syncthreads();

    // ---- Phase 1a: stage 3D half, coalesced (lane = sample) ----
    {
        const float* p3 = f3d + ((size_t)b * C3D) * NSAMP + n0 + lane;
        #pragma unroll
        for (int i = 0; i < C3D / 4; ++i) {
            const int c = wv + i * 4;
            cat[C2D + c][lane] = p3[(size_t)c * NSAMP];
        }
    }

    // ---- Phase 1b: gather 2D half. Wave wv -> channels [32wv, 32wv+32),
    // lane = sample. 4 scalar gathers per (channel, sample). ----
    {
        const float w0 = sw[0][lane], w1 = sw[1][lane];
        const float w2 = sw[2][lane], w3 = sw[3][lane];
        const int o0 = soff[0][lane], o1 = soff[1][lane];
        const int o2 = soff[2][lane], o3 = soff[3][lane];
        const float* p2 = f2d + ((size_t)(b * C2D + wv * 32)) * HW;
        #pragma unroll 4
        for (int c = 0; c < 32; ++c) {
            const float* pc = p2 + (size_t)c * HW;
            float v = w0 * pc[o0] + w1 * pc[o1] + w2 * pc[o2] + w3 * pc[o3];
            cat[wv * 32 + c][lane] = v;
        }
    }
    __syncthreads();

    // ---- Phase 2: GEMM. Wave wv computes co in [32wv, 32wv+32) for its
    // 64 samples (lane = sample). W rows are wave-uniform -> scalar loads. ----
    {
        const int co0 = __builtin_amdgcn_readfirstlane(wv * 32);
        float acc[32];
        #pragma unroll
        for (int i = 0; i < 32; ++i) acc[i] = 0.0f;

        #pragma unroll 1
        for (int kc = 0; kc < KK; kc += 8) {
            float cr[8];
            #pragma unroll
            for (int kk = 0; kk < 8; ++kk) cr[kk] = cat[kc + kk][lane];
            #pragma unroll
            for (int i = 0; i < 32; ++i) {
                const float* wr = Wm + (size_t)(co0 + i) * KK + kc;
                #pragma unroll
                for (int kk = 0; kk < 8; ++kk)
                    acc[i] = fmaf(wr[kk], cr[kk], acc[i]);
            }
        }

        float* po = out + ((size_t)b * COUT + co0) * NSAMP + n0 + lane;
        #pragma unroll
        for (int i = 0; i < 32; ++i) {
            float yv = acc[i] + bias[co0 + i];
            yv = (yv >= 0.0f) ? yv : 0.1f * yv;   // leaky relu, slope 0.1
            po[(size_t)i * NSAMP] = yv;
        }
    }
}

extern "C" void kernel_launch(void* const* d_in, const int* in_sizes, int n_in,
                              void* d_out, int out_size, void* d_ws, size_t ws_size,
                              hipStream_t stream) {
    const float* xy   = (const float*)d_in[0];
    const float* f2d  = (const float*)d_in[1];
    const float* f3d  = (const float*)d_in[2];
    const float* Wm   = (const float*)d_in[3];
    const float* bias = (const float*)d_in[4];
    float* out = (float*)d_out;

    dim3 grid(BB * (NSAMP / TN));   // 1024 blocks
    fuse_kernel<<<grid, 256, 0, stream>>>(xy, f2d, f3d, Wm, bias, out);
}

// Round 2
// 222.929 us; speedup vs baseline: 1.5053x; 1.5053x over previous
//
#include <hip/hip_runtime.h>

// Problem constants (fixed by setup_inputs)
#define NSAMP 16384   // N
#define BB    4       // batch
#define C2D   128
#define C3D   128
#define HH    96
#define WW    160
#define COUT  128
#define KK    256     // fan_in = C2D + C3D
#define TN    64      // samples per block
#define HW    (HH*WW) // 15360

// ---------------------------------------------------------------------------
// Kernel 1: transpose f2d [B,C2D,H,W] -> ws [B,H*W,C2D] (channel-last).
// Tiled through LDS so both global read and write are fully coalesced.
// ---------------------------------------------------------------------------
__global__ __launch_bounds__(256) void transpose_kernel(
    const float* __restrict__ f2d, float* __restrict__ ws)
{
    __shared__ float t[64][C2D + 1];   // +1 pad: conflict-free both phases
    const int tid  = threadIdx.x;
    const int lane = tid & 63;
    const int wv   = tid >> 6;
    const int blk  = blockIdx.x;
    const int b    = blk / (HW / 64);
    const int hw0  = (blk % (HW / 64)) * 64;

    // read: lanes sweep hw (coalesced 256B), wave wv covers 32 channels
    #pragma unroll
    for (int i = 0; i < 32; ++i) {
        const int c = wv * 32 + i;
        t[lane][c] = f2d[(size_t)(b * C2D + c) * HW + hw0 + lane];
    }
    __syncthreads();
    // write: consecutive threads sweep c (coalesced 1KB per wave-instr)
    #pragma unroll
    for (int i = 0; i < 32; ++i) {
        const int flat = i * 256 + tid;
        const int j = flat >> 7;       // hw-in-tile
        const int c = flat & 127;
        ws[(size_t)(b * HW + hw0 + j) * C2D + c] = t[j][c];
    }
}

// ---------------------------------------------------------------------------
// Kernel 2: fused bilinear-gather + concat-GEMM + leaky-relu.
// One block: batch b, samples [n0, n0+TN). 256 threads = 4 waves.
// LDS: cat2[TN][C2D+1] fp32 (~33 KB) -> 4 blocks/CU.
// TRANSPOSED: gather from channel-last ws (fast path) vs raw f2d (fallback
// if ws_size is too small — same numerics, just slow).
// ---------------------------------------------------------------------------
template <bool TRANSPOSED>
__global__ __launch_bounds__(256, 4) void fuse_kernel(
    const float*  __restrict__ xy,     // [B,2,N]
    const float*  __restrict__ f2dx,   // TRANSPOSED ? [B,HW,C2D] : [B,C2D,H,W]
    const float*  __restrict__ f3d,    // [B,C3D,N]
    const float*  __restrict__ Wm,     // [COUT,KK]
    const float*  __restrict__ bias,   // [COUT]
    float* __restrict__ out)           // [B,COUT,N]
{
    __shared__ float  cat2[TN][C2D + 1];  // gathered 2D half, [sample][chan]
    __shared__ float4 sw4[TN];            // 4 corner weights per sample
    __shared__ int4   soff4[TN];          // 4 corner plane-offsets per sample

    const int tid  = threadIdx.x;
    const int lane = tid & 63;
    const int wv   = tid >> 6;        // wave id 0..3
    const int blk  = blockIdx.x;
    const int b    = blk >> 8;        // N/TN = 256 tiles per batch
    const int n0   = (blk & 255) * TN;

    // ---- Phase 0: bilinear params for the 64 samples ----
    if (tid < TN) {
        const int n = n0 + tid;
        float x = xy[((size_t)b * 2 + 0) * NSAMP + n];
        float y = xy[((size_t)b * 2 + 1) * NSAMP + n];
        float xf = floorf(x), yf = floorf(y);
        float wx1 = x - xf, wy1 = y - yf;
        float wx0 = 1.0f - wx1, wy0 = 1.0f - wy1;
        int x0 = (int)xf, y0 = (int)yf;
        int x1 = x0 + 1, y1 = y0 + 1;
        // zero weights for out-of-bounds corners (reference: valid-mask * value)
        if (x0 < 0 || x0 > WW - 1) wx0 = 0.0f;
        if (x1 < 0 || x1 > WW - 1) wx1 = 0.0f;
        if (y0 < 0 || y0 > HH - 1) wy0 = 0.0f;
        if (y1 < 0 || y1 > HH - 1) wy1 = 0.0f;
        x0 = min(max(x0, 0), WW - 1);
        x1 = min(max(x1, 0), WW - 1);
        y0 = min(max(y0, 0), HH - 1);
        y1 = min(max(y1, 0), HH - 1);
        sw4[tid]   = make_float4(wx0 * wy0, wx1 * wy0, wx0 * wy1, wx1 * wy1);
        soff4[tid] = make_int4(y0 * WW + x0, y0 * WW + x1,
                               y1 * WW + x0, y1 * WW + x1);
    }
    __syncthreads();

    // ---- Phase 1: gather 2D half into cat2 ----
    if (TRANSPOSED) {
        // Wave wv handles samples j in [16wv, 16wv+16). Lane holds channels
        // (2*lane, 2*lane+1). Each corner is 512 contiguous bytes -> one
        // fully-coalesced float2 load per wave.
        const int c2 = lane * 2;
        const float* fb = f2dx + (size_t)b * HW * C2D + c2;
        #pragma unroll 2
        for (int jj = 0; jj < 16; ++jj) {
            const int j = wv * 16 + jj;
            const float4 w = sw4[j];        // uniform addr -> broadcast
            const int4   o = soff4[j];
            const float2 v0 = *(const float2*)(fb + (size_t)o.x * C2D);
            const float2 v1 = *(const float2*)(fb + (size_t)o.y * C2D);
            const float2 v2 = *(const float2*)(fb + (size_t)o.z * C2D);
            const float2 v3 = *(const float2*)(fb + (size_t)o.w * C2D);
            float r0 = w.x * v0.x + w.y * v1.x + w.z * v2.x + w.w * v3.x;
            float r1 = w.x * v0.y + w.y * v1.y + w.z * v2.y + w.w * v3.y;
            *(float2*)&cat2[j][c2] = make_float2(r0, r1);  // contiguous 128-word run
        }
    } else {
        // Fallback: divergent gather from raw layout (slow but correct).
        const float4 w = sw4[lane];
        const int4   o = soff4[lane];
        const float* p2 = f2dx + (size_t)(b * C2D + wv * 32) * HW;
        #pragma unroll 4
        for (int c = 0; c < 32; ++c) {
            const float* pc = p2 + (size_t)c * HW;
            cat2[lane][wv * 32 + c] =
                w.x * pc[o.x] + w.y * pc[o.y] + w.z * pc[o.z] + w.w * pc[o.w];
        }
    }
    __syncthreads();

    // ---- Phase 2: GEMM. Wave wv computes co in [32wv, 32wv+32) for the 64
    // samples (lane = sample). W rows wave-uniform -> scalar loads.
    // K-half 1 (2D) from LDS; K-half 2 (3D) coalesced straight from global.
    {
        const int co0 = __builtin_amdgcn_readfirstlane(wv * 32);
        float acc[32];
        #pragma unroll
        for (int i = 0; i < 32; ++i) acc[i] = 0.0f;

        // 2D half (k = 0..127) from LDS
        #pragma unroll 1
        for (int kc = 0; kc < C2D; kc += 8) {
            float cr[8];
            #pragma unroll
            for (int kk = 0; kk < 8; ++kk) cr[kk] = cat2[lane][kc + kk];
            #pragma unroll
            for (int i = 0; i < 32; ++i) {
                const float* wr = Wm + (size_t)(co0 + i) * KK + kc;
                #pragma unroll
                for (int kk = 0; kk < 8; ++kk)
                    acc[i] = fmaf(wr[kk], cr[kk], acc[i]);
            }
        }

        // 3D half (k = 128..255) direct from global, coalesced (lane = sample)
        const float* p3 = f3d + (size_t)b * C3D * NSAMP + n0 + lane;
        #pragma unroll 1
        for (int kc = 0; kc < C3D; kc += 8) {
            float cr[8];
            #pragma unroll
            for (int kk = 0; kk < 8; ++kk) cr[kk] = p3[(size_t)(kc + kk) * NSAMP];
            #pragma unroll
            for (int i = 0; i < 32; ++i) {
                const float* wr = Wm + (size_t)(co0 + i) * KK + C2D + kc;
                #pragma unroll
                for (int kk = 0; kk < 8; ++kk)
                    acc[i] = fmaf(wr[kk], cr[kk], acc[i]);
            }
        }

        float* po = out + (size_t)(b * COUT + co0) * NSAMP + n0 + lane;
        #pragma unroll
        for (int i = 0; i < 32; ++i) {
            float yv = acc[i] + bias[co0 + i];
            yv = (yv >= 0.0f) ? yv : 0.1f * yv;   // leaky relu, slope 0.1
            po[(size_t)i * NSAMP] = yv;
        }
    }
}

extern "C" void kernel_launch(void* const* d_in, const int* in_sizes, int n_in,
                              void* d_out, int out_size, void* d_ws, size_t ws_size,
                              hipStream_t stream) {
    const float* xy   = (const float*)d_in[0];
    const float* f2d  = (const float*)d_in[1];
    const float* f3d  = (const float*)d_in[2];
    const float* Wm   = (const float*)d_in[3];
    const float* bias = (const float*)d_in[4];
    float* out = (float*)d_out;

    const size_t need = (size_t)BB * HW * C2D * sizeof(float);  // 31.5 MB
    dim3 grid(BB * (NSAMP / TN));   // 1024 blocks

    if (ws_size >= need) {
        float* f2dt = (float*)d_ws;
        transpose_kernel<<<dim3(BB * (HW / 64)), 256, 0, stream>>>(f2d, f2dt);
        fuse_kernel<true><<<grid, 256, 0, stream>>>(xy, f2dt, f3d, Wm, bias, out);
    } else {
        fuse_kernel<false><<<grid, 256, 0, stream>>>(xy, f2d, f3d, Wm, bias, out);
    }
}

// Round 3
// 127.500 us; speedup vs baseline: 2.6320x; 1.7485x over previous
//
#include <hip/hip_runtime.h>
#include <hip/hip_bf16.h>

// Problem constants (fixed by setup_inputs)
#define NSAMP 16384   // N
#define BB    4       // batch
#define C2D   128
#define C3D   128
#define HH    96
#define WW    160
#define COUT  128
#define KK    256     // fan_in
#define TN    64      // samples per fuse block
#define HW    (HH*WW) // 15360
#define CATS  264     // cat row stride in bf16 elems: 256 + 8 pad = 132 words (sigma=33 odd
                      // -> conflict-free b128/b64 at 16-lane row strides, 16B-aligned rows)

typedef __attribute__((ext_vector_type(8))) short bf16x8;  // 8 bf16 = 4 VGPRs (MFMA A/B frag)
typedef __attribute__((ext_vector_type(4))) float f32x4;   // MFMA C/D frag

__device__ __forceinline__ float bf16lo(unsigned int u) { return __uint_as_float(u << 16); }
__device__ __forceinline__ float bf16hi(unsigned int u) { return __uint_as_float(u & 0xffff0000u); }
__device__ __forceinline__ unsigned int pack2(float a, float b) {
    union { __hip_bfloat162 h; unsigned int u; } c;
    c.h = __float22bfloat162_rn(make_float2(a, b));   // RNE, x in low 16 bits
    return c.u;
}

// ---------------------------------------------------------------------------
// Kernel 1: f2d fp32 [B,C2D,H,W] -> f2dt bf16 channel-last [B,HW,C2D].
// Tile = 64 hw x 64 c. 1920 blocks. Both global sides coalesced; both LDS
// phases conflict-free (row stride 33 words, bank = (hw + c/2) % 32).
// ---------------------------------------------------------------------------
__global__ __launch_bounds__(256) void transpose_cvt_kernel(
    const float* __restrict__ f2d, unsigned short* __restrict__ f2dt)
{
    __shared__ unsigned short t[64 * 66];   // [hw_local][c_local], 66 shorts/row = 33 words
    const int tid  = threadIdx.x;
    const int lane = tid & 63;
    const int wv   = tid >> 6;
    const int blk  = blockIdx.x;
    const int b    = blk / ((HW / 64) * 2);
    const int rem  = blk % ((HW / 64) * 2);
    const int c0   = (rem & 1) * 64;
    const int hw0  = (rem >> 1) * 64;

    // read: lane sweeps hw (coalesced 256B/instr), one channel per wave per step
    #pragma unroll
    for (int s = 0; s < 16; ++s) {
        const int cl = s * 4 + wv;
        float v = f2d[(size_t)(b * C2D + c0 + cl) * HW + hw0 + lane];
        __hip_bfloat16 h = __float2bfloat16(v);
        t[lane * 66 + cl] = *(unsigned short*)&h;
    }
    __syncthreads();
    // write: channel-last rows, uint (2 channels) per lane, 128B runs
    const unsigned int* tw  = (const unsigned int*)t;
    unsigned int*       wsu = (unsigned int*)f2dt;
    #pragma unroll
    for (int s = 0; s < 8; ++s) {
        const int hwl = s * 8 + (tid >> 5);
        const int cu  = tid & 31;
        wsu[((size_t)(b * HW + hw0 + hwl) * C2D + c0) / 2 + cu] = tw[hwl * 33 + cu];
    }
}

// ---------------------------------------------------------------------------
// Kernel 2: W fp32 [COUT,KK] -> bf16 row-major (A-fragment-friendly).
// ---------------------------------------------------------------------------
__global__ __launch_bounds__(256) void wcvt_kernel(
    const float* __restrict__ Wm, unsigned short* __restrict__ Wb)
{
    const int i = blockIdx.x * 256 + threadIdx.x;   // 8192 threads x 4 elems
    const float4 v = ((const float4*)Wm)[i];
    uint2 o;
    o.x = pack2(v.x, v.y);
    o.y = pack2(v.z, v.w);
    ((uint2*)Wb)[i] = o;
}

// ---------------------------------------------------------------------------
// Kernel 3: fused bilinear-gather + concat + bf16 MFMA GEMM + bias + leaky.
// Block = (batch b, 64 samples). 256 threads = 4 waves.
// cat LDS rows: [n][k] bf16, k=0..127 gathered 2D, k=128..255 f3d.
// MFMA 16x16x32_bf16: A = Wb rows (global, L2-hot), B = cat rows (LDS).
// Wave wv: co in [32wv,32wv+32) (2 mtiles) x all 4 ntiles.
// ---------------------------------------------------------------------------
__global__ __launch_bounds__(256, 4) void fuse_kernel(
    const float*          __restrict__ xy,     // [B,2,N]
    const unsigned short* __restrict__ f2dt,   // [B,HW,C2D] bf16
    const float*          __restrict__ f3d,    // [B,C3D,N]
    const unsigned short* __restrict__ Wb,     // [COUT,KK] bf16
    const float*          __restrict__ bias,   // [COUT]
    float* __restrict__ out)                   // [B,COUT,N]
{
    __shared__ unsigned short cat[TN * CATS];
    __shared__ float4 sw4[TN];
    __shared__ int4   soff4[TN];

    const int tid  = threadIdx.x;
    const int lane = tid & 63;
    const int wv   = tid >> 6;
    const int blk  = blockIdx.x;
    const int b    = blk >> 8;            // 256 tiles per batch
    const int n0   = (blk & 255) * TN;

    // ---- Phase 0: bilinear params ----
    if (tid < TN) {
        const int n = n0 + tid;
        float x = xy[((size_t)b * 2 + 0) * NSAMP + n];
        float y = xy[((size_t)b * 2 + 1) * NSAMP + n];
        float xf = floorf(x), yf = floorf(y);
        float wx1 = x - xf, wy1 = y - yf;
        float wx0 = 1.0f - wx1, wy0 = 1.0f - wy1;
        int x0 = (int)xf, y0 = (int)yf;
        int x1 = x0 + 1, y1 = y0 + 1;
        if (x0 < 0 || x0 > WW - 1) wx0 = 0.0f;
        if (x1 < 0 || x1 > WW - 1) wx1 = 0.0f;
        if (y0 < 0 || y0 > HH - 1) wy0 = 0.0f;
        if (y1 < 0 || y1 > HH - 1) wy1 = 0.0f;
        x0 = min(max(x0, 0), WW - 1);
        x1 = min(max(x1, 0), WW - 1);
        y0 = min(max(y0, 0), HH - 1);
        y1 = min(max(y1, 0), HH - 1);
        sw4[tid]   = make_float4(wx0 * wy0, wx1 * wy0, wx0 * wy1, wx1 * wy1);
        soff4[tid] = make_int4(y0 * WW + x0, y0 * WW + x1,
                               y1 * WW + x0, y1 * WW + x1);
    }
    __syncthreads();

    unsigned int* catw = (unsigned int*)cat;

    // ---- Phase 1a: f3d -> cat[n][128+c], bf16. lane = sample, wave wv covers
    // 32 channels. Coalesced 4B loads; b128 LDS writes (conflict-free). ----
    {
        const float* p3 = f3d + (size_t)(b * C3D) * NSAMP + n0 + lane;
        #pragma unroll
        for (int ch = 0; ch < 4; ++ch) {
            const int cbase = wv * 32 + ch * 8;
            float v[8];
            #pragma unroll
            for (int t = 0; t < 8; ++t) v[t] = p3[(size_t)(cbase + t) * NSAMP];
            uint4 pk;
            pk.x = pack2(v[0], v[1]);
            pk.y = pack2(v[2], v[3]);
            pk.z = pack2(v[4], v[5]);
            pk.w = pack2(v[6], v[7]);
            *(uint4*)&catw[lane * (CATS / 2) + (C2D / 2) + (cbase >> 1)] = pk;
        }
    }

    // ---- Phase 1b: gather 2D corners (256B bf16 rows) + blend -> cat[n][c].
    // Half-wave per sample: lane -> (sample s, 4 channels). ----
    {
        const int s   = lane >> 5;
        const int ch4 = (lane & 31) * 4;
        const unsigned short* fb = f2dt + (size_t)b * HW * C2D + ch4;
        #pragma unroll 4
        for (int i = 0; i < 8; ++i) {
            const int j = wv * 16 + i * 2 + s;
            const float4 w = sw4[j];
            const int4   o = soff4[j];
            const uint2 c0v = *(const uint2*)(fb + (size_t)o.x * C2D);
            const uint2 c1v = *(const uint2*)(fb + (size_t)o.y * C2D);
            const uint2 c2v = *(const uint2*)(fb + (size_t)o.z * C2D);
            const uint2 c3v = *(const uint2*)(fb + (size_t)o.w * C2D);
            float r0 = w.x * bf16lo(c0v.x) + w.y * bf16lo(c1v.x)
                     + w.z * bf16lo(c2v.x) + w.w * bf16lo(c3v.x);
            float r1 = w.x * bf16hi(c0v.x) + w.y * bf16hi(c1v.x)
                     + w.z * bf16hi(c2v.x) + w.w * bf16hi(c3v.x);
            float r2 = w.x * bf16lo(c0v.y) + w.y * bf16lo(c1v.y)
                     + w.z * bf16lo(c2v.y) + w.w * bf16lo(c3v.y);
            float r3 = w.x * bf16hi(c0v.y) + w.y * bf16hi(c1v.y)
                     + w.z * bf16hi(c2v.y) + w.w * bf16hi(c3v.y);
            uint2 pk;
            pk.x = pack2(r0, r1);
            pk.y = pack2(r2, r3);
            *(uint2*)&catw[j * (CATS / 2) + (ch4 >> 1)] = pk;
        }
    }
    __syncthreads();

    // ---- Phase 2: MFMA GEMM, D[128 x 64] = Wb[128 x 256] @ cat^T ----
    {
        const int quad = lane >> 4;
        const int nloc = lane & 15;

        f32x4 acc[2][4];
        #pragma unroll
        for (int mt = 0; mt < 2; ++mt)
            #pragma unroll
            for (int nt = 0; nt < 4; ++nt)
                acc[mt][nt] = (f32x4){0.f, 0.f, 0.f, 0.f};

        // A-fragment base: row co = 32wv + mt*16 + nloc(=m), k = k0 + quad*8 + j
        const unsigned short* wb0 = Wb + (size_t)(wv * 32 + nloc) * KK + quad * 8;

        #pragma unroll 2
        for (int ks = 0; ks < 8; ++ks) {
            const int k0 = ks * 32;
            const bf16x8 a0 = *(const bf16x8*)(wb0 + k0);
            const bf16x8 a1 = *(const bf16x8*)(wb0 + 16 * KK + k0);
            #pragma unroll
            for (int nt = 0; nt < 4; ++nt) {
                // B-frag: B[k][n] = cat[n][k], n = nloc, k = k0 + quad*8 + j
                const bf16x8 bfrag = *(const bf16x8*)
                    &cat[(nt * 16 + nloc) * CATS + k0 + quad * 8];
                acc[0][nt] = __builtin_amdgcn_mfma_f32_16x16x32_bf16(
                    a0, bfrag, acc[0][nt], 0, 0, 0);
                acc[1][nt] = __builtin_amdgcn_mfma_f32_16x16x32_bf16(
                    a1, bfrag, acc[1][nt], 0, 0, 0);
            }
        }

        // Epilogue: bias + leaky-relu; C/D layout col=lane&15, row=quad*4+r
        #pragma unroll
        for (int mt = 0; mt < 2; ++mt) {
            const int cobase = wv * 32 + mt * 16 + quad * 4;
            float bv[4];
            #pragma unroll
            for (int r = 0; r < 4; ++r) bv[r] = bias[cobase + r];
            #pragma unroll
            for (int nt = 0; nt < 4; ++nt) {
                float* po = out + (size_t)(b * COUT + cobase) * NSAMP
                          + n0 + nt * 16 + nloc;
                #pragma unroll
                for (int r = 0; r < 4; ++r) {
                    float yv = acc[mt][nt][r] + bv[r];
                    yv = (yv >= 0.0f) ? yv : 0.1f * yv;
                    po[(size_t)r * NSAMP] = yv;
                }
            }
        }
    }
}

extern "C" void kernel_launch(void* const* d_in, const int* in_sizes, int n_in,
                              void* d_out, int out_size, void* d_ws, size_t ws_size,
                              hipStream_t stream) {
    const float* xy   = (const float*)d_in[0];
    const float* f2d  = (const float*)d_in[1];
    const float* f3d  = (const float*)d_in[2];
    const float* Wm   = (const float*)d_in[3];
    const float* bias = (const float*)d_in[4];
    float* out = (float*)d_out;

    // ws layout: f2dt bf16 [B*HW*C2D] then Wb bf16 [COUT*KK]
    unsigned short* f2dt = (unsigned short*)d_ws;
    unsigned short* Wb   = f2dt + (size_t)BB * HW * C2D;
    // total need ~15.8 MB; round-2 evidence shows ws_size >= 31.5 MB

    wcvt_kernel<<<dim3((COUT * KK / 4) / 256), 256, 0, stream>>>(Wm, Wb);
    transpose_cvt_kernel<<<dim3(BB * (HW / 64) * 2), 256, 0, stream>>>(f2d, f2dt);
    fuse_kernel<<<dim3(BB * (NSAMP / TN)), 256, 0, stream>>>(
        xy, f2dt, f3d, Wb, bias, out);
}